// Round 8
// baseline (284.286 us; speedup 1.0000x reference)
//
#include <hip/hip_runtime.h>
#include <math.h>

#define UDIM 256
#define BATCH 64
#define MATN 65536   // 256*256
#define PITCH 280    // LDS row pitch (bf16): 560B = 16B-aligned

typedef __bf16 bf16x8 __attribute__((ext_vector_type(8)));
typedef float  f32x4  __attribute__((ext_vector_type(4)));

__device__ __forceinline__ float softplusf(float x) { return log1pf(expf(x)); }
__device__ __forceinline__ float sigmoidf_(float x) { return 1.f/(1.f+expf(-x)); }

// Fragment-direct layout (verified): chunk(rt,kt) = rows rt*16..+15 x k
// kt*32..+31; lane = (row&15) | ((k>>3)&3)<<4; 8 contiguous bf16 per lane.
__device__ __forceinline__ bf16x8 frag_load(const __bf16* base, int rt, int kt, int lane) {
  return *(const bf16x8*)(base + (((size_t)(rt*8 + kt))*64 + lane)*8);
}

__device__ __forceinline__ bf16x8 cvt8(const float* p) {
  const float4 f0 = *(const float4*)p;
  const float4 f1 = *(const float4*)(p + 4);
  bf16x8 v;
  v[0]=(__bf16)f0.x; v[1]=(__bf16)f0.y; v[2]=(__bf16)f0.z; v[3]=(__bf16)f0.w;
  v[4]=(__bf16)f1.x; v[5]=(__bf16)f1.y; v[6]=(__bf16)f1.z; v[7]=(__bf16)f1.w;
  return v;
}

#define MFMA16 __builtin_amdgcn_mfma_f32_16x16x32_bf16

// ---------------------------------------------------------------------------
// prep_all (round-4 verbatim): grid 1136.
// scal: xx[0..63], pp[64..127], trS[128..191], gg[192..255] (atomic),
//       trG[256..319] (atomic, in quad_all). cnt/riders live after scal.
// ---------------------------------------------------------------------------
__global__ __launch_bounds__(256) void prep_all(
    const float* __restrict__ Uz, const float* __restrict__ Wz,
    const float* __restrict__ Ur, const float* __restrict__ Wr,
    const float* __restrict__ Uh, const float* __restrict__ Wh,
    __bf16* __restrict__ Fw_z, __bf16* __restrict__ Fw_r,
    __bf16* __restrict__ Fu_h, __bf16* __restrict__ Fw_h,
    const float* __restrict__ S, const float* __restrict__ x,
    const float* __restrict__ prev, float* __restrict__ scal,
    __bf16* __restrict__ Sf,
    float* __restrict__ zb, float* __restrict__ rb,
    float* __restrict__ gzb, float* __restrict__ grb,
    float* __restrict__ gin)
{
  const int bid = blockIdx.x;
  const int t = threadIdx.x;
  const int w = t >> 6, l = t & 63, r = l & 15, q = l >> 4;

  __shared__ __align__(16) unsigned char LDSU[16896];

  if (bid < 1024) {
    const int c = bid;
    const int bx = c & 3, by = (c >> 2) & 3, b = c >> 4;
    const size_t sb = (size_t)b * MATN;
#pragma unroll
    for (int ss = 0; ss < 2; ++ss) {
      const int s = t + ss*256;
      const int chunk = s >> 6, lane = s & 63;
      const int rt_l = chunk >> 1, kt_l = chunk & 1;
      const int row = by*64 + rt_l*16 + (lane & 15);
      const int col = bx*64 + kt_l*32 + (lane >> 4)*8;
      const bf16x8 v = cvt8(S + sb + (size_t)row*UDIM + col);
      *(bf16x8*)(Sf + sb + (((size_t)((by*4 + rt_l)*8 + bx*2 + kt_l))*64 + lane)*8) = v;
    }
    return;
  }

  if (bid < 1088) {
    const int u3 = bid - 1024;
    const int mat = u3 >> 4, tl = u3 & 15;
    const int n0 = (tl & 3)*64, k0 = (tl >> 2)*64;
    const float* W; __bf16* F;
    switch (mat) {
      case 0: W = Wz; F = Fw_z; break;  case 1: W = Wr; F = Fw_r; break;
      case 2: W = Uh; F = Fu_h; break;  default: W = Wh; F = Fw_h; break;
    }
    float (*tile)[65] = (float (*)[65])LDSU;
    const int tx = t & 15, ty = t >> 4;
#pragma unroll
    for (int rr = 0; rr < 4; ++rr) {
      const int row = ty*4 + rr;
      const float4 f = *(const float4*)(W + (size_t)(k0 + row)*UDIM + n0 + tx*4);
      tile[row][tx*4+0] = f.x; tile[row][tx*4+1] = f.y;
      tile[row][tx*4+2] = f.z; tile[row][tx*4+3] = f.w;
    }
    __syncthreads();
#pragma unroll
    for (int ss = 0; ss < 2; ++ss) {
      const int s = t + ss*256;
      const int rt_l = s >> 7, kt_l = (s >> 6) & 1, lane = s & 63;
      const int nl = rt_l*16 + (lane & 15), kb = kt_l*32 + (lane >> 4)*8;
      __align__(16) __bf16 tmp[8];
#pragma unroll
      for (int e = 0; e < 8; ++e) tmp[e] = (__bf16)tile[kb + e][nl];
      *(uint4*)(F + (((size_t)((((n0 >> 4) + rt_l)*8) + (k0 >> 5) + kt_l))*64 + lane)*8)
          = *(const uint4*)tmp;
    }
    return;
  }

  if (bid < 1104) {
    const int blk = bid - 1088;
    const int b0 = blk*4 + (t >> 6);
    const float4 xv = *(const float4*)(x + b0*UDIM + l*4);
    float s0 = xv.x*xv.x + xv.y*xv.y + xv.z*xv.z + xv.w*xv.w;
    const float4 pv = *(const float4*)(prev + b0*UDIM + l*4);
    float s1 = pv.x*pv.x + pv.y*pv.y + pv.z*pv.z + pv.w*pv.w;
    float s2 = 0.f;
#pragma unroll
    for (int e = 0; e < 4; ++e)
      s2 += S[(size_t)b0*MATN + (size_t)(l*4 + e)*257];
    for (int off = 32; off; off >>= 1) {
      s0 += __shfl_down(s0, off);
      s1 += __shfl_down(s1, off);
      s2 += __shfl_down(s2, off);
    }
    if (l == 0) { scal[b0] = s0; scal[64 + b0] = s1; scal[128 + b0] = s2; }
    return;
  }

  // ---- z/r gates with self-transposed weight slices ----
  {
    const int u2 = bid - 1104;
    const int g = u2 >> 4, un = u2 & 15;
    const int n0 = un * 16;
    const float* Um = g ? Ur : Uz;
    const float* Wm = g ? Wr : Wz;
    __bf16 (*Ut)[16][264] = (__bf16 (*)[16][264])LDSU;
    {
      float uv[16], wv[16];
      const float* ur_ = Um + (size_t)t*UDIM + n0;
      const float* wr_ = Wm + (size_t)t*UDIM + n0;
#pragma unroll
      for (int p4 = 0; p4 < 4; ++p4) {
        *(float4*)&uv[p4*4] = *(const float4*)(ur_ + p4*4);
        *(float4*)&wv[p4*4] = *(const float4*)(wr_ + p4*4);
      }
#pragma unroll
      for (int e = 0; e < 16; ++e) {
        Ut[0][e][t] = (__bf16)uv[e];
        Ut[1][e][t] = (__bf16)wv[e];
      }
    }
    __syncthreads();

    const int mrow = w*16 + r;
    f32x4 acc = {};
#pragma unroll
    for (int ks = 0; ks < 16; ++ks) {
      const int k0 = ks*32;
      const float* asrc;
      int src, koff;
      if (k0 < 256) { asrc = x    + (size_t)mrow*UDIM + k0         + q*8; src = 0; koff = k0; }
      else          { asrc = prev + (size_t)mrow*UDIM + (k0 - 256) + q*8; src = 1; koff = k0 - 256; }
      const bf16x8 af = cvt8(asrc);
      const bf16x8 bv = *(const bf16x8*)&Ut[src][r][koff + q*8];
      acc = MFMA16(af, bv, acc, 0, 0, 0);
    }
    const int n = n0 + r;
    if (g == 0) {
#pragma unroll
      for (int v = 0; v < 4; ++v) {
        const int m = w*16 + q*4 + v;
        const float zv = sigmoidf_(acc[v]);
        zb[m*UDIM + n]  = zv;
        gzb[m*UDIM + n] = zv * (1.f - zv);
      }
    } else {
      float ggp[4];
#pragma unroll
      for (int v = 0; v < 4; ++v) {
        const int m = w*16 + q*4 + v;
        const float rv = sigmoidf_(acc[v]);
        const float pv = prev[m*UDIM + n];
        const float g2 = pv * rv;
        rb[m*UDIM + n]  = rv;
        grb[m*UDIM + n] = rv * (1.f - rv);
        gin[m*UDIM + n] = g2;
        ggp[v] = g2 * g2;
      }
#pragma unroll
      for (int s2 = 1; s2 < 16; s2 <<= 1)
#pragma unroll
        for (int v = 0; v < 4; ++v) ggp[v] += __shfl_xor(ggp[v], s2);
      if (r == 0)
#pragma unroll
        for (int v = 0; v < 4; ++v)
          atomicAdd(&scal[192 + w*16 + q*4 + v], ggp[v]);
    }
  }
}

// ---------------------------------------------------------------------------
// quad_all: grid EXACTLY 1024 (=256 CU x 4 blocks, all co-resident by
// resource math: LB(256,4) caps VGPR at 128, LDS 17920B -> 4 blocks/CU).
// Block (s = bid>>6, b = bid&63):
//   [rider-lite, only s==15 && b>=48]: 16-column h-gate tile (warms Fw_h on
//     every XCD), fence + riders++.
//   Phase 1: fused z/r quad for (s,b).  Szb strip kept in o16 REGISTERS
//     (buffer deleted), S strip kept in Sv regs.  G_b + trG written.
//     fence + cnt[b]++.
//   Spin: cnt[b]==16 (G_b complete, same-XCD L2-warm) && riders==16.
//   Phase 2: quad_h for (s,b) reusing o16/Sv/prev regs; out_sig write.
// ---------------------------------------------------------------------------
__global__ __launch_bounds__(256, 4) void quad_all(
    const float* __restrict__ S, const __bf16* __restrict__ Sf,
    const float* __restrict__ prev,
    const float* __restrict__ rb, const float* __restrict__ gzb,
    const float* __restrict__ grb,
    const float* __restrict__ wz_s, const float* __restrict__ uz_s,
    const float* __restrict__ wr_s, const float* __restrict__ ur_s,
    const float* __restrict__ wh_s, const float* __restrict__ uh_s,
    const __bf16* __restrict__ Fw_z, const __bf16* __restrict__ Fw_r,
    const __bf16* __restrict__ Fu_h, const __bf16* __restrict__ Fw_h,
    float* __restrict__ scal, unsigned int* __restrict__ cnt,
    __bf16* __restrict__ G,
    const float* __restrict__ x, const float* __restrict__ gin,
    const float* __restrict__ zb,
    float* __restrict__ hb, float* __restrict__ ghb,
    float* __restrict__ mu_out, float* __restrict__ out_sig)
{
  const int bid = blockIdx.x;
  const int s = bid >> 6, b = bid & 63;
  const int t = threadIdx.x, w = t >> 6, l = t & 63, r = l & 15, q = l >> 4;
  const size_t sb = (size_t)b * MATN;
  const __bf16* Sfb = Sf + sb;

  __shared__ __align__(16) __bf16 T[2*16*PITCH];
  __bf16* Tz = T;
  __bf16* Tr = T + 16*PITCH;

  // ---- rider-lite: h-gate 16-column tile (16 blocks, all XCDs) ----
  if (s == 15 && b >= 48) {
    const int un = b - 48;              // 0..15 -> columns un*16..+15
    const int mrow = w*16 + r;
    f32x4 acc = {};
#pragma unroll
    for (int kq = 0; kq < 4; ++kq) {
      bf16x8 af[4], bv[4];
#pragma unroll
      for (int u = 0; u < 4; ++u) {
        const int k0 = (kq*4 + u)*32;
        if (k0 < 256) {
          af[u] = cvt8(x   + (size_t)mrow*UDIM + k0 + q*8);
          bv[u] = frag_load(Fu_h, un, k0 >> 5, l);
        } else {
          af[u] = cvt8(gin + (size_t)mrow*UDIM + (k0 - 256) + q*8);
          bv[u] = frag_load(Fw_h, un, (k0 - 256) >> 5, l);
        }
      }
#pragma unroll
      for (int u = 0; u < 4; ++u) acc = MFMA16(af[u], bv[u], acc, 0, 0, 0);
    }
    const int n = un*16 + r;
#pragma unroll
    for (int v = 0; v < 4; ++v) {
      const int m = w*16 + q*4 + v;
      const float hv = tanhf(acc[v]);
      const float zv = zb[m*UDIM + n];
      hb[m*UDIM + n]  = hv;
      ghb[m*UDIM + n] = 1.f - hv*hv;
      mu_out[m*UDIM + n] = zv * prev[m*UDIM + n] + (1.f - zv) * hv;
    }
    __syncthreads();
    if (t == 0) { __threadfence(); atomicAdd(&cnt[64], 1u); }
  }

  // ================= Phase 1: fused z/r quad =================
  f32x4 az[4] = {}, ar[4] = {};
#pragma unroll
  for (int kp = 0; kp < 4; ++kp) {
    bf16x8 wzf[2], wrf[2], sv[2][4];
#pragma unroll
    for (int u = 0; u < 2; ++u) {
      const int kt = kp*2 + u;
      wzf[u] = frag_load(Fw_z, s, kt, l);
      wrf[u] = frag_load(Fw_r, s, kt, l);
#pragma unroll
      for (int ct = 0; ct < 4; ++ct) sv[u][ct] = frag_load(Sfb, w*4 + ct, kt, l);
    }
#pragma unroll
    for (int u = 0; u < 2; ++u)
#pragma unroll
      for (int ct = 0; ct < 4; ++ct) {
        az[ct] = MFMA16(wzf[u], sv[u][ct], az[ct], 0, 0, 0);
        ar[ct] = MFMA16(wrf[u], sv[u][ct], ar[ct], 0, 0, 0);
      }
  }
#pragma unroll
  for (int ct = 0; ct < 4; ++ct)
#pragma unroll
    for (int v = 0; v < 4; ++v) {
      Tz[(q*4 + v)*PITCH + w*64 + ct*16 + r] = (__bf16)az[ct][v];
      Tr[(q*4 + v)*PITCH + w*64 + ct*16 + r] = (__bf16)ar[ct][v];
    }
  __syncthreads();

  // epilogue operand prefetch (hidden under right GEMMs); Sv/pjv retained
  const int ib = s*16 + q*4;
  const f32x4 gz4 = *(const f32x4*)(gzb + b*UDIM + ib);
  const f32x4 gr4 = *(const f32x4*)(grb + b*UDIM + ib);
  const f32x4 pp4 = *(const f32x4*)(prev + b*UDIM + ib);
  const f32x4 rr4 = *(const f32x4*)(rb + b*UDIM + ib);
  float Sv[16], pjv[4];
#pragma unroll
  for (int ct = 0; ct < 4; ++ct) {
    const int j = (w*4 + ct)*16 + r;
    pjv[ct] = prev[b*UDIM + j];
#pragma unroll
    for (int v = 0; v < 4; ++v)
      Sv[ct*4 + v] = S[sb + (size_t)(ib + v)*UDIM + j];
  }
  const float xx = scal[b];
  const float dscal = scal[64 + b] + scal[128 + b];   // pp + trS

  // right GEMMs from LDS
  f32x4 qz[4] = {}, qr[4] = {};
#pragma unroll
  for (int kt = 0; kt < 8; ++kt) {
    bf16x8 bwz[4], bwr[4];
#pragma unroll
    for (int ct = 0; ct < 4; ++ct) {
      bwz[ct] = frag_load(Fw_z, w*4 + ct, kt, l);
      bwr[ct] = frag_load(Fw_r, w*4 + ct, kt, l);
    }
    const bf16x8 atz = *(const bf16x8*)&Tz[r*PITCH + kt*32 + q*8];
    const bf16x8 atr = *(const bf16x8*)&Tr[r*PITCH + kt*32 + q*8];
#pragma unroll
    for (int ct = 0; ct < 4; ++ct) {
      qz[ct] = MFMA16(atz, bwz[ct], qz[ct], 0, 0, 0);
      qr[ct] = MFMA16(atr, bwr[ct], qr[ct], 0, 0, 0);
    }
  }

  // z epilogue -> o16 REGISTERS ONLY (Szb buffer deleted)
  __align__(16) __bf16 o16[16];
#pragma unroll
  for (int ct = 0; ct < 4; ++ct) {
    const int j = (w*4 + ct)*16 + r;
    const float gj = gzb[b*UDIM + j];
#pragma unroll
    for (int v = 0; v < 4; ++v) {
      const int i = ib + v;
      float qv = qz[ct][v];
      if (i == j) qv += dscal*softplusf(wz_s[i]) + xx*softplusf(uz_s[i]);
      o16[ct*4 + v] = (__bf16)(qv * gz4[v] * gj);
    }
  }

  // r epilogue -> sigma_g + trG, bounce through Tr -> G
  {
    float gvals[16];
    float trg = 0.f;
#pragma unroll
    for (int ct = 0; ct < 4; ++ct) {
      const int j = (w*4 + ct)*16 + r;
      const float gj = grb[b*UDIM + j];
      const float rj = rb[b*UDIM + j];
#pragma unroll
      for (int v = 0; v < 4; ++v) {
        const int i = ib + v;
        float qv = qr[ct][v];
        if (i == j) qv += dscal*softplusf(wr_s[i]) + xx*softplusf(ur_s[i]);
        const float Sg = qv * gr4[v] * gj;
        const float sv = Sv[ct*4 + v];
        const float go = Sg*(sv + pp4[v]*pjv[ct]) + rr4[v]*rj*sv;
        gvals[ct*4 + v] = go;
        if (i == j) trg += go;
      }
    }
    if (trg != 0.f) atomicAdd(&scal[256 + b], trg);

    __syncthreads();            // all right-GEMM Tr reads complete
#pragma unroll
    for (int ct = 0; ct < 4; ++ct)
#pragma unroll
      for (int v = 0; v < 4; ++v)
        Tr[(q*4 + v)*PITCH + w*64 + ct*16 + r] = (__bf16)gvals[ct*4 + v];
    __syncthreads();
#pragma unroll
    for (int ee = 0; ee < 2; ++ee) {
      const int e = t + ee*256;
      const int kt = e >> 6, le = e & 63;
      const uint4 vv = *(const uint4*)&Tr[(le & 15)*PITCH + kt*32 + (le >> 4)*8];
      *(uint4*)(G + sb + (((size_t)(s*8 + kt))*64 + le)*8) = vv;
    }
  }

  // ================= per-batch barrier =================
  __syncthreads();
  if (t == 0) {
    __threadfence();
    atomicAdd(&cnt[b], 1u);
    while (__hip_atomic_load(&cnt[b], __ATOMIC_RELAXED, __HIP_MEMORY_SCOPE_AGENT) < 16u
        || __hip_atomic_load(&cnt[64], __ATOMIC_RELAXED, __HIP_MEMORY_SCOPE_AGENT) < 16u)
      __builtin_amdgcn_s_sleep(2);
    __threadfence();
  }
  __syncthreads();

  // ================= Phase 2: quad_h for (s,b) =================
  {
    const __bf16* Gb = G + sb;
    __bf16* Th = T;

    f32x4 ah[4] = {};
#pragma unroll
    for (int kp = 0; kp < 4; ++kp) {
      bf16x8 af[2], bv[2][4];
#pragma unroll
      for (int u = 0; u < 2; ++u) {
        const int kt = kp*2 + u;
        af[u] = frag_load(Fw_h, s, kt, l);
#pragma unroll
        for (int ct = 0; ct < 4; ++ct) bv[u][ct] = frag_load(Gb, w*4 + ct, kt, l);
      }
#pragma unroll
      for (int u = 0; u < 2; ++u)
#pragma unroll
        for (int ct = 0; ct < 4; ++ct)
          ah[ct] = MFMA16(af[u], bv[u][ct], ah[ct], 0, 0, 0);
    }
#pragma unroll
    for (int ct = 0; ct < 4; ++ct)
#pragma unroll
      for (int v = 0; v < 4; ++v)
        Th[(q*4 + v)*PITCH + w*64 + ct*16 + r] = (__bf16)ah[ct][v];
    __syncthreads();

    // epilogue operand prefetch (ghb/zb/hb rows; Sv/pjv/pp4/o16 retained)
    const f32x4 g4 = *(const f32x4*)(ghb + b*UDIM + ib);
    const f32x4 z4 = *(const f32x4*)(zb + b*UDIM + ib);
    const f32x4 h4 = *(const f32x4*)(hb + b*UDIM + ib);
    float gjv[4], zjv[4], hjv[4];
#pragma unroll
    for (int ct = 0; ct < 4; ++ct) {
      const int j = (w*4 + ct)*16 + r;
      gjv[ct] = ghb[b*UDIM + j];
      zjv[ct] = zb[b*UDIM + j];
      hjv[ct] = hb[b*UDIM + j];
    }
    const float dsch = scal[192 + b] + scal[256 + b];  // gg + trG

    f32x4 qh[4] = {};
#pragma unroll
    for (int kt = 0; kt < 8; ++kt) {
      bf16x8 bw[4];
#pragma unroll
      for (int ct = 0; ct < 4; ++ct) bw[ct] = frag_load(Fw_h, w*4 + ct, kt, l);
      const bf16x8 at = *(const bf16x8*)&Th[r*PITCH + kt*32 + q*8];
#pragma unroll
      for (int ct = 0; ct < 4; ++ct)
        qh[ct] = MFMA16(at, bw[ct], qh[ct], 0, 0, 0);
    }

#pragma unroll
    for (int ct = 0; ct < 4; ++ct) {
      const int j = (w*4 + ct)*16 + r;
#pragma unroll
      for (int v = 0; v < 4; ++v) {
        const int i = ib + v;
        float qv = qh[ct][v];
        if (i == j) qv += dsch*softplusf(wh_s[i]) + xx*softplusf(uh_s[i]);
        const float Sg = qv * g4[v] * gjv[ct];
        const float sv = Sv[ct*4 + v];
        const float sz = (float)o16[ct*4 + v];
        float val = sv*(sz + z4[v]*zjv[ct])
                  + sz*(pp4[v] - h4[v])*(pjv[ct] - hjv[ct])
                  + Sg*(sz + (1.f - z4[v])*(1.f - zjv[ct]));
        if (!isfinite(val)) val = 0.f;
        if (i == j) val = fabsf(val);
        out_sig[sb + (size_t)i*UDIM + j] = val;
      }
    }
  }
}

// ---------------------------------------------------------------------------
extern "C" void kernel_launch(void* const* d_in, const int* in_sizes, int n_in,
                              void* d_out, int out_size, void* d_ws, size_t ws_size,
                              hipStream_t stream) {
  const float* x    = (const float*)d_in[0];
  const float* prev = (const float*)d_in[1];
  const float* S    = (const float*)d_in[2];
  const float* Uz   = (const float*)d_in[3];
  const float* uz_s = (const float*)d_in[4];
  const float* Wz   = (const float*)d_in[5];
  const float* wz_s = (const float*)d_in[6];
  const float* Ur   = (const float*)d_in[7];
  const float* ur_s = (const float*)d_in[8];
  const float* Wr   = (const float*)d_in[9];
  const float* wr_s = (const float*)d_in[10];
  const float* Uh   = (const float*)d_in[11];
  const float* uh_s = (const float*)d_in[12];
  const float* Wh   = (const float*)d_in[13];
  const float* wh_s = (const float*)d_in[14];

  float* out_mu  = (float*)d_out;
  float* out_sig = out_mu + BATCH*UDIM;

  float* ws   = (float*)d_ws;
  float* zb   = ws;
  float* rb   = zb  + BATCH*UDIM;
  float* gzb  = rb  + BATCH*UDIM;
  float* grb  = gzb + BATCH*UDIM;
  float* gin  = grb + BATCH*UDIM;
  float* hb   = gin + BATCH*UDIM;
  float* ghb  = hb  + BATCH*UDIM;
  float* scal = ghb + BATCH*UDIM;            // 512 floats
  unsigned int* cnt = (unsigned int*)(scal + 512);   // 65 uints (64 batch + riders)
  __bf16* bws  = (__bf16*)(scal + 512 + 80);
  __bf16* Fw_z = bws;
  __bf16* Fw_r = Fw_z + MATN;
  __bf16* Fu_h = Fw_r + MATN;
  __bf16* Fw_h = Fu_h + MATN;
  const size_t BIG = (size_t)BATCH * MATN;
  __bf16* G   = Fw_h + MATN;                 // [B,U,U] bf16 fragment-direct
  __bf16* Sf  = G + BIG;                     // [B,U,U] bf16 fragment-direct

  (void)hipMemsetAsync(scal, 0, (512 + 80)*sizeof(float), stream);

  prep_all<<<dim3(1136), 256, 0, stream>>>(Uz, Wz, Ur, Wr, Uh, Wh,
      Fw_z, Fw_r, Fu_h, Fw_h, S, x, prev, scal, Sf,
      zb, rb, gzb, grb, gin);
  quad_all<<<dim3(1024), 256, 0, stream>>>(S, Sf, prev, rb, gzb, grb,
      wz_s, uz_s, wr_s, ur_s, wh_s, uh_s,
      Fw_z, Fw_r, Fu_h, Fw_h, scal, cnt, G,
      x, gin, zb, hb, ghb, out_mu, out_sig);
}

// Round 10
// 162.605 us; speedup vs baseline: 1.7483x; 1.7483x over previous
//
#include <hip/hip_runtime.h>
#include <math.h>

#define UDIM 256
#define BATCH 64
#define MATN 65536   // 256*256
#define PITCH 280    // LDS row pitch (bf16): 560B = 16B-aligned
#define GG_BASE 256
#define TRG_BASE 1280

typedef __bf16 bf16x8 __attribute__((ext_vector_type(8)));
typedef float  f32x4  __attribute__((ext_vector_type(4)));

__device__ __forceinline__ float softplusf(float x) { return log1pf(expf(x)); }
__device__ __forceinline__ float sigmoidf_(float x) { return 1.f/(1.f+expf(-x)); }

// Fragment-direct layout (verified): chunk(rt,kt) = rows rt*16..+15 x k
// kt*32..+31; lane = (row&15) | ((k>>3)&3)<<4; 8 contiguous bf16 per lane.
__device__ __forceinline__ bf16x8 frag_load(const __bf16* base, int rt, int kt, int lane) {
  return *(const bf16x8*)(base + (((size_t)(rt*8 + kt))*64 + lane)*8);
}

__device__ __forceinline__ bf16x8 cvt8(const float* p) {
  const float4 f0 = *(const float4*)p;
  const float4 f1 = *(const float4*)(p + 4);
  bf16x8 v;
  v[0]=(__bf16)f0.x; v[1]=(__bf16)f0.y; v[2]=(__bf16)f0.z; v[3]=(__bf16)f0.w;
  v[4]=(__bf16)f1.x; v[5]=(__bf16)f1.y; v[6]=(__bf16)f1.z; v[7]=(__bf16)f1.w;
  return v;
}

#define MFMA16 __builtin_amdgcn_mfma_f32_16x16x32_bf16

// ---------------------------------------------------------------------------
// prep_all: grid EXACTLY 1024 (one resident round).  Every block converts one
// S->Sf chunk; blocks 0..111 ALSO carry a special role first:
//   0..63 : weight transposes Wz/Wr/Uh/Wh -> fragment-direct bf16
//   64..79: scalar reductions xx/pp/trS (plain stores)
//   80..111: z/r gates with self-transposed weight slices; GG partials to
//            unique slots scal[GG_BASE + m*16 + un] (no atomics, no memset).
// ---------------------------------------------------------------------------
__global__ __launch_bounds__(256) void prep_all(
    const float* __restrict__ Uz, const float* __restrict__ Wz,
    const float* __restrict__ Ur, const float* __restrict__ Wr,
    const float* __restrict__ Uh, const float* __restrict__ Wh,
    __bf16* __restrict__ Fw_z, __bf16* __restrict__ Fw_r,
    __bf16* __restrict__ Fu_h, __bf16* __restrict__ Fw_h,
    const float* __restrict__ S, const float* __restrict__ x,
    const float* __restrict__ prev, float* __restrict__ scal,
    __bf16* __restrict__ Sf,
    float* __restrict__ zb, float* __restrict__ rb,
    float* __restrict__ gzb, float* __restrict__ grb,
    float* __restrict__ gin)
{
  const int bid = blockIdx.x;
  const int t = threadIdx.x;
  const int w = t >> 6, l = t & 63, r = l & 15, q = l >> 4;

  __shared__ __align__(16) unsigned char LDSU[16896];

  if (bid < 64) {
    // ---- weight transpose role ----
    const int mat = bid >> 4, tl = bid & 15;
    const int n0 = (tl & 3)*64, k0 = (tl >> 2)*64;
    const float* W; __bf16* F;
    switch (mat) {
      case 0: W = Wz; F = Fw_z; break;  case 1: W = Wr; F = Fw_r; break;
      case 2: W = Uh; F = Fu_h; break;  default: W = Wh; F = Fw_h; break;
    }
    float (*tile)[65] = (float (*)[65])LDSU;
    const int tx = t & 15, ty = t >> 4;
#pragma unroll
    for (int rr = 0; rr < 4; ++rr) {
      const int row = ty*4 + rr;
      const float4 f = *(const float4*)(W + (size_t)(k0 + row)*UDIM + n0 + tx*4);
      tile[row][tx*4+0] = f.x; tile[row][tx*4+1] = f.y;
      tile[row][tx*4+2] = f.z; tile[row][tx*4+3] = f.w;
    }
    __syncthreads();
#pragma unroll
    for (int ss = 0; ss < 2; ++ss) {
      const int s = t + ss*256;
      const int rt_l = s >> 7, kt_l = (s >> 6) & 1, lane = s & 63;
      const int nl = rt_l*16 + (lane & 15), kb = kt_l*32 + (lane >> 4)*8;
      __align__(16) __bf16 tmp[8];
#pragma unroll
      for (int e = 0; e < 8; ++e) tmp[e] = (__bf16)tile[kb + e][nl];
      *(uint4*)(F + (((size_t)((((n0 >> 4) + rt_l)*8) + (k0 >> 5) + kt_l))*64 + lane)*8)
          = *(const uint4*)tmp;
    }
  } else if (bid < 80) {
    // ---- scalar reductions role ----
    const int blk = bid - 64;
    const int b0 = blk*4 + (t >> 6);
    const float4 xv = *(const float4*)(x + b0*UDIM + l*4);
    float s0 = xv.x*xv.x + xv.y*xv.y + xv.z*xv.z + xv.w*xv.w;
    const float4 pv = *(const float4*)(prev + b0*UDIM + l*4);
    float s1 = pv.x*pv.x + pv.y*pv.y + pv.z*pv.z + pv.w*pv.w;
    float s2 = 0.f;
#pragma unroll
    for (int e = 0; e < 4; ++e)
      s2 += S[(size_t)b0*MATN + (size_t)(l*4 + e)*257];
    for (int off = 32; off; off >>= 1) {
      s0 += __shfl_down(s0, off);
      s1 += __shfl_down(s1, off);
      s2 += __shfl_down(s2, off);
    }
    if (l == 0) { scal[b0] = s0; scal[64 + b0] = s1; scal[128 + b0] = s2; }
  } else if (bid < 112) {
    // ---- z/r gates role (self-transposed weight slices) ----
    const int u2 = bid - 80;
    const int g = u2 >> 4, un = u2 & 15;
    const int n0 = un * 16;
    const float* Um = g ? Ur : Uz;
    const float* Wm = g ? Wr : Wz;
    __bf16 (*Ut)[16][264] = (__bf16 (*)[16][264])LDSU;
    {
      float uv[16], wv[16];
      const float* ur_ = Um + (size_t)t*UDIM + n0;
      const float* wr_ = Wm + (size_t)t*UDIM + n0;
#pragma unroll
      for (int p4 = 0; p4 < 4; ++p4) {
        *(float4*)&uv[p4*4] = *(const float4*)(ur_ + p4*4);
        *(float4*)&wv[p4*4] = *(const float4*)(wr_ + p4*4);
      }
#pragma unroll
      for (int e = 0; e < 16; ++e) {
        Ut[0][e][t] = (__bf16)uv[e];
        Ut[1][e][t] = (__bf16)wv[e];
      }
    }
    __syncthreads();

    const int mrow = w*16 + r;
    f32x4 acc = {};
#pragma unroll
    for (int ks = 0; ks < 16; ++ks) {
      const int k0 = ks*32;
      const float* asrc;
      int src, koff;
      if (k0 < 256) { asrc = x    + (size_t)mrow*UDIM + k0         + q*8; src = 0; koff = k0; }
      else          { asrc = prev + (size_t)mrow*UDIM + (k0 - 256) + q*8; src = 1; koff = k0 - 256; }
      const bf16x8 af = cvt8(asrc);
      const bf16x8 bv = *(const bf16x8*)&Ut[src][r][koff + q*8];
      acc = MFMA16(af, bv, acc, 0, 0, 0);
    }
    const int n = n0 + r;
    if (g == 0) {
#pragma unroll
      for (int v = 0; v < 4; ++v) {
        const int m = w*16 + q*4 + v;
        const float zv = sigmoidf_(acc[v]);
        zb[m*UDIM + n]  = zv;
        gzb[m*UDIM + n] = zv * (1.f - zv);
      }
    } else {
      float ggp[4];
#pragma unroll
      for (int v = 0; v < 4; ++v) {
        const int m = w*16 + q*4 + v;
        const float rv = sigmoidf_(acc[v]);
        const float pv = prev[m*UDIM + n];
        const float g2 = pv * rv;
        rb[m*UDIM + n]  = rv;
        grb[m*UDIM + n] = rv * (1.f - rv);
        gin[m*UDIM + n] = g2;
        ggp[v] = g2 * g2;
      }
#pragma unroll
      for (int s2 = 1; s2 < 16; s2 <<= 1)
#pragma unroll
        for (int v = 0; v < 4; ++v) ggp[v] += __shfl_xor(ggp[v], s2);
      if (r == 0)
#pragma unroll
        for (int v = 0; v < 4; ++v)
          scal[GG_BASE + (w*16 + q*4 + v)*16 + un] = ggp[v];   // unique slot
    }
  }

  // ---- all blocks: S -> Sf fragment-direct bf16 conversion (chunk = bid) ----
  {
    const int c = bid;
    const int bx = c & 3, by = (c >> 2) & 3, b = c >> 4;
    const size_t sb = (size_t)b * MATN;
#pragma unroll
    for (int ss = 0; ss < 2; ++ss) {
      const int s = t + ss*256;
      const int chunk = s >> 6, lane = s & 63;
      const int rt_l = chunk >> 1, kt_l = chunk & 1;
      const int row = by*64 + rt_l*16 + (lane & 15);
      const int col = bx*64 + kt_l*32 + (lane >> 4)*8;
      const bf16x8 v = cvt8(S + sb + (size_t)row*UDIM + col);
      *(bf16x8*)(Sf + sb + (((size_t)((by*4 + rt_l)*8 + bx*2 + kt_l))*64 + lane)*8) = v;
    }
  }
}

// ---------------------------------------------------------------------------
// quad_zr_gh: grid EXACTLY 1024 (one resident round).  Block (s,b), fused
// z/r gates, batched loads (round-7 proven).  The 4 gates_h rider tiles are
// folded onto blocks 1020..1023 (rider first, then main quad) — no extra
// blocks, no second dispatch round.  trG block-reduced to unique slot
// scal[TRG_BASE + b*16 + s] (no atomics).
// ---------------------------------------------------------------------------
__global__ __launch_bounds__(256, 4) void quad_zr_gh(
    const float* __restrict__ S, const __bf16* __restrict__ Sf,
    const float* __restrict__ prev,
    const float* __restrict__ rb, const float* __restrict__ gzb,
    const float* __restrict__ grb,
    const float* __restrict__ wz_s, const float* __restrict__ uz_s,
    const float* __restrict__ wr_s, const float* __restrict__ ur_s,
    const __bf16* __restrict__ Fw_z, const __bf16* __restrict__ Fw_r,
    float* __restrict__ scal, __bf16* __restrict__ Szb, __bf16* __restrict__ G,
    const float* __restrict__ x, const float* __restrict__ gin,
    const float* __restrict__ zb,
    const __bf16* __restrict__ Fu_h, const __bf16* __restrict__ Fw_h,
    float* __restrict__ hb, float* __restrict__ ghb, float* __restrict__ mu_out)
{
  const int bid = blockIdx.x;
  const int t = threadIdx.x, w = t >> 6, l = t & 63, r = l & 15, q = l >> 4;
  const int s = bid >> 6, b = bid & 63;

  __shared__ __align__(16) __bf16 T[2*16*PITCH];
  __shared__ float red4[4];
  __bf16* Tz = T;
  __bf16* Tr = T + 16*PITCH;

  if (bid >= 1020) {
    // ---- gates_h rider (folded; jt = bid-1020), runs before main quad ----
    const int jt = bid - 1020;
    const int mrow = w*16 + r;
    f32x4 acc[4] = {};
#pragma unroll
    for (int ks = 0; ks < 16; ++ks) {
      const int k0 = ks*32;
      const float* asrc; const __bf16* B; int kk;
      if (k0 < 256) { asrc = x   + (size_t)mrow*UDIM + k0         + q*8; B = Fu_h; kk = k0; }
      else          { asrc = gin + (size_t)mrow*UDIM + (k0 - 256) + q*8; B = Fw_h; kk = k0 - 256; }
      const bf16x8 af = cvt8(asrc);
#pragma unroll
      for (int ni = 0; ni < 4; ++ni) {
        const bf16x8 bv = frag_load(B, jt*4 + ni, kk >> 5, l);
        acc[ni] = MFMA16(af, bv, acc[ni], 0, 0, 0);
      }
    }
#pragma unroll
    for (int ni = 0; ni < 4; ++ni) {
      const int n = jt*64 + ni*16 + r;
#pragma unroll
      for (int v = 0; v < 4; ++v) {
        const int m = w*16 + q*4 + v;
        const float hv = tanhf(acc[ni][v]);
        const float zv = zb[m*UDIM + n];
        hb[m*UDIM + n]  = hv;
        ghb[m*UDIM + n] = 1.f - hv*hv;
        mu_out[m*UDIM + n] = zv * prev[m*UDIM + n] + (1.f - zv) * hv;
      }
    }
  }

  const size_t sb = (size_t)b * MATN;
  const __bf16* Sfb = Sf + sb;

  // ---- left GEMMs: kt-pair batched loads, each Sf frag feeds both gates ----
  f32x4 az[4] = {}, ar[4] = {};
#pragma unroll
  for (int kp = 0; kp < 4; ++kp) {
    bf16x8 wzf[2], wrf[2], sv[2][4];
#pragma unroll
    for (int u = 0; u < 2; ++u) {
      const int kt = kp*2 + u;
      wzf[u] = frag_load(Fw_z, s, kt, l);
      wrf[u] = frag_load(Fw_r, s, kt, l);
#pragma unroll
      for (int ct = 0; ct < 4; ++ct) sv[u][ct] = frag_load(Sfb, w*4 + ct, kt, l);
    }
#pragma unroll
    for (int u = 0; u < 2; ++u)
#pragma unroll
      for (int ct = 0; ct < 4; ++ct) {
        az[ct] = MFMA16(wzf[u], sv[u][ct], az[ct], 0, 0, 0);
        ar[ct] = MFMA16(wrf[u], sv[u][ct], ar[ct], 0, 0, 0);
      }
  }
#pragma unroll
  for (int ct = 0; ct < 4; ++ct)
#pragma unroll
    for (int v = 0; v < 4; ++v) {
      Tz[(q*4 + v)*PITCH + w*64 + ct*16 + r] = (__bf16)az[ct][v];
      Tr[(q*4 + v)*PITCH + w*64 + ct*16 + r] = (__bf16)ar[ct][v];
    }
  __syncthreads();

  // ---- epilogue operand prefetch (hides under right GEMMs) ----
  const int ib = s*16 + q*4;
  const f32x4 gz4 = *(const f32x4*)(gzb + b*UDIM + ib);
  const f32x4 gr4 = *(const f32x4*)(grb + b*UDIM + ib);
  const f32x4 pp4 = *(const f32x4*)(prev + b*UDIM + ib);
  const f32x4 rr4 = *(const f32x4*)(rb + b*UDIM + ib);
  float Sv[16];
#pragma unroll
  for (int ct = 0; ct < 4; ++ct)
#pragma unroll
    for (int v = 0; v < 4; ++v)
      Sv[ct*4 + v] = S[sb + (size_t)(ib + v)*UDIM + (w*4 + ct)*16 + r];
  const float xx = scal[b];
  const float dscal = scal[64 + b] + scal[128 + b];   // pp + trS

  // ---- right GEMMs from LDS (per-kt batched FW loads) ----
  f32x4 qz[4] = {}, qr[4] = {};
#pragma unroll
  for (int kt = 0; kt < 8; ++kt) {
    bf16x8 bwz[4], bwr[4];
#pragma unroll
    for (int ct = 0; ct < 4; ++ct) {
      bwz[ct] = frag_load(Fw_z, w*4 + ct, kt, l);
      bwr[ct] = frag_load(Fw_r, w*4 + ct, kt, l);
    }
    const bf16x8 atz = *(const bf16x8*)&Tz[r*PITCH + kt*32 + q*8];
    const bf16x8 atr = *(const bf16x8*)&Tr[r*PITCH + kt*32 + q*8];
#pragma unroll
    for (int ct = 0; ct < 4; ++ct) {
      qz[ct] = MFMA16(atz, bwz[ct], qz[ct], 0, 0, 0);
      qr[ct] = MFMA16(atr, bwr[ct], qr[ct], 0, 0, 0);
    }
  }

  // ---- z epilogue -> Szb (C-linear bf16) ----
  {
    __align__(16) __bf16 o16[16];
#pragma unroll
    for (int ct = 0; ct < 4; ++ct) {
      const int j = (w*4 + ct)*16 + r;
      const float gj = gzb[b*UDIM + j];
#pragma unroll
      for (int v = 0; v < 4; ++v) {
        const int i = ib + v;
        float qv = qz[ct][v];
        if (i == j) qv += dscal*softplusf(wz_s[i]) + xx*softplusf(uz_s[i]);
        o16[ct*4 + v] = (__bf16)(qv * gz4[v] * gj);
      }
    }
    __bf16* dst = Szb + ((size_t)(b*16 + s)*256 + t)*16;
    *(uint4*)dst       = *(const uint4*)&o16[0];
    *(uint4*)(dst + 8) = *(const uint4*)&o16[8];
  }

  // ---- r epilogue -> sigma_g + trG (block-reduced), bounce Tr -> G ----
  {
    float gvals[16];
    float trg = 0.f;
#pragma unroll
    for (int ct = 0; ct < 4; ++ct) {
      const int j = (w*4 + ct)*16 + r;
      const float gj = grb[b*UDIM + j];
      const float pj = prev[b*UDIM + j];
      const float rj = rb[b*UDIM + j];
#pragma unroll
      for (int v = 0; v < 4; ++v) {
        const int i = ib + v;
        float qv = qr[ct][v];
        if (i == j) qv += dscal*softplusf(wr_s[i]) + xx*softplusf(ur_s[i]);
        const float Sg = qv * gr4[v] * gj;
        const float sv = Sv[ct*4 + v];
        const float go = Sg*(sv + pp4[v]*pj) + rr4[v]*rj*sv;
        gvals[ct*4 + v] = go;
        if (i == j) trg += go;
      }
    }
    // block-reduce trg -> unique slot (no atomic, no memset needed)
    for (int off = 32; off; off >>= 1) trg += __shfl_down(trg, off);
    if (l == 0) red4[w] = trg;

    __syncthreads();            // all right-GEMM Tr reads complete; red4 ready
    if (t == 0)
      scal[TRG_BASE + b*16 + s] = red4[0] + red4[1] + red4[2] + red4[3];
#pragma unroll
    for (int ct = 0; ct < 4; ++ct)
#pragma unroll
      for (int v = 0; v < 4; ++v)
        Tr[(q*4 + v)*PITCH + w*64 + ct*16 + r] = (__bf16)gvals[ct*4 + v];
    __syncthreads();
#pragma unroll
    for (int ee = 0; ee < 2; ++ee) {
      const int e = t + ee*256;
      const int kt = e >> 6, le = e & 63;
      const uint4 vv = *(const uint4*)&Tr[(le & 15)*PITCH + kt*32 + (le >> 4)*8];
      *(uint4*)(G + sb + (((size_t)(s*8 + kt))*64 + le)*8) = vv;
    }
  }
}

// ---------------------------------------------------------------------------
// quad_h: grid 1024 (exact), one strip per block, batched loads + prefetch.
// dscal = sum of GG[b*16..+15] + TRG[b*16..+15] (8 vector loads, prefetched).
// ---------------------------------------------------------------------------
__global__ __launch_bounds__(256, 4) void quad_h(
    const float* __restrict__ S, const __bf16* __restrict__ Szb,
    const float* __restrict__ prev, const float* __restrict__ zb,
    const float* __restrict__ hb, const float* __restrict__ ghb,
    const float* __restrict__ wh_s, const float* __restrict__ uh_s,
    const __bf16* __restrict__ Fw_h, const __bf16* __restrict__ G,
    const float* __restrict__ scal, float* __restrict__ out_sig)
{
  const int bid = blockIdx.x;
  const int s = bid >> 6, b = bid & 63;
  const size_t sb = (size_t)b * MATN;
  const int t = threadIdx.x, w = t >> 6, l = t & 63, r = l & 15, q = l >> 4;
  const __bf16* Gb = G + sb;

  __shared__ __align__(16) __bf16 Th[16*PITCH];

  // ---- left GEMM: kt-pair batched loads ----
  f32x4 ah[4] = {};
#pragma unroll
  for (int kp = 0; kp < 4; ++kp) {
    bf16x8 af[2], bv[2][4];
#pragma unroll
    for (int u = 0; u < 2; ++u) {
      const int kt = kp*2 + u;
      af[u] = frag_load(Fw_h, s, kt, l);
#pragma unroll
      for (int ct = 0; ct < 4; ++ct) bv[u][ct] = frag_load(Gb, w*4 + ct, kt, l);
    }
#pragma unroll
    for (int u = 0; u < 2; ++u)
#pragma unroll
      for (int ct = 0; ct < 4; ++ct)
        ah[ct] = MFMA16(af[u], bv[u][ct], ah[ct], 0, 0, 0);
  }
#pragma unroll
  for (int ct = 0; ct < 4; ++ct)
#pragma unroll
    for (int v = 0; v < 4; ++v)
      Th[(q*4 + v)*PITCH + w*64 + ct*16 + r] = (__bf16)ah[ct][v];
  __syncthreads();

  // ---- epilogue operand prefetch (hides under right GEMM) ----
  const int ib = s*16 + q*4;
  const __bf16* szp = Szb + ((size_t)(b*16 + s)*256 + t)*16;
  __align__(16) __bf16 sz16[16];
  *(uint4*)&sz16[0] = *(const uint4*)szp;
  *(uint4*)&sz16[8] = *(const uint4*)(szp + 8);
  const f32x4 g4 = *(const f32x4*)(ghb + b*UDIM + ib);
  const f32x4 p4 = *(const f32x4*)(prev + b*UDIM + ib);
  const f32x4 z4 = *(const f32x4*)(zb + b*UDIM + ib);
  const f32x4 h4 = *(const f32x4*)(hb + b*UDIM + ib);
  float Sv[16], gjv[4], pjv[4], zjv[4], hjv[4];
#pragma unroll
  for (int ct = 0; ct < 4; ++ct) {
    const int j = (w*4 + ct)*16 + r;
    gjv[ct] = ghb[b*UDIM + j];
    pjv[ct] = prev[b*UDIM + j];
    zjv[ct] = zb[b*UDIM + j];
    hjv[ct] = hb[b*UDIM + j];
#pragma unroll
    for (int v = 0; v < 4; ++v)
      Sv[ct*4 + v] = S[sb + (size_t)(ib + v)*UDIM + j];
  }
  const float xx = scal[b];
  float dscal = 0.f;
#pragma unroll
  for (int e = 0; e < 4; ++e) {
    const f32x4 a = *(const f32x4*)(scal + GG_BASE + b*16 + e*4);
    const f32x4 c = *(const f32x4*)(scal + TRG_BASE + b*16 + e*4);
    dscal += a[0]+a[1]+a[2]+a[3] + c[0]+c[1]+c[2]+c[3];
  }

  // ---- right GEMM from LDS ----
  f32x4 qh[4] = {};
#pragma unroll
  for (int kt = 0; kt < 8; ++kt) {
    bf16x8 bw[4];
#pragma unroll
    for (int ct = 0; ct < 4; ++ct) bw[ct] = frag_load(Fw_h, w*4 + ct, kt, l);
    const bf16x8 at = *(const bf16x8*)&Th[r*PITCH + kt*32 + q*8];
#pragma unroll
    for (int ct = 0; ct < 4; ++ct)
      qh[ct] = MFMA16(at, bw[ct], qh[ct], 0, 0, 0);
  }

#pragma unroll
  for (int ct = 0; ct < 4; ++ct) {
    const int j = (w*4 + ct)*16 + r;
#pragma unroll
    for (int v = 0; v < 4; ++v) {
      const int i = ib + v;
      float qv = qh[ct][v];
      if (i == j) qv += dscal*softplusf(wh_s[i]) + xx*softplusf(uh_s[i]);
      const float Sg = qv * g4[v] * gjv[ct];
      const float sv = Sv[ct*4 + v];
      const float sz = (float)sz16[ct*4 + v];
      float val = sv*(sz + z4[v]*zjv[ct])
                + sz*(p4[v] - h4[v])*(pjv[ct] - hjv[ct])
                + Sg*(sz + (1.f - z4[v])*(1.f - zjv[ct]));
      if (!isfinite(val)) val = 0.f;
      if (i == j) val = fabsf(val);
      out_sig[sb + (size_t)i*UDIM + j] = val;
    }
  }
}

// ---------------------------------------------------------------------------
extern "C" void kernel_launch(void* const* d_in, const int* in_sizes, int n_in,
                              void* d_out, int out_size, void* d_ws, size_t ws_size,
                              hipStream_t stream) {
  const float* x    = (const float*)d_in[0];
  const float* prev = (const float*)d_in[1];
  const float* S    = (const float*)d_in[2];
  const float* Uz   = (const float*)d_in[3];
  const float* uz_s = (const float*)d_in[4];
  const float* Wz   = (const float*)d_in[5];
  const float* wz_s = (const float*)d_in[6];
  const float* Ur   = (const float*)d_in[7];
  const float* ur_s = (const float*)d_in[8];
  const float* Wr   = (const float*)d_in[9];
  const float* wr_s = (const float*)d_in[10];
  const float* Uh   = (const float*)d_in[11];
  const float* uh_s = (const float*)d_in[12];
  const float* Wh   = (const float*)d_in[13];
  const float* wh_s = (const float*)d_in[14];

  float* out_mu  = (float*)d_out;
  float* out_sig = out_mu + BATCH*UDIM;

  float* ws   = (float*)d_ws;
  float* zb   = ws;
  float* rb   = zb  + BATCH*UDIM;
  float* gzb  = rb  + BATCH*UDIM;
  float* grb  = gzb + BATCH*UDIM;
  float* gin  = grb + BATCH*UDIM;
  float* hb   = gin + BATCH*UDIM;
  float* ghb  = hb  + BATCH*UDIM;
  float* scal = ghb + BATCH*UDIM;            // 2304 floats (all unique-slot)
  __bf16* bws  = (__bf16*)(scal + 2304);
  __bf16* Fw_z = bws;
  __bf16* Fw_r = Fw_z + MATN;
  __bf16* Fu_h = Fw_r + MATN;
  __bf16* Fw_h = Fu_h + MATN;
  const size_t BIG = (size_t)BATCH * MATN;
  __bf16* Szb = Fw_h + MATN;                 // [B,16,256,16] bf16 C-linear
  __bf16* G   = Szb + BIG;                   // [B,U,U] bf16 fragment-direct
  __bf16* Sf  = G + BIG;                     // [B,U,U] bf16 fragment-direct

  prep_all<<<dim3(1024), 256, 0, stream>>>(Uz, Wz, Ur, Wr, Uh, Wh,
      Fw_z, Fw_r, Fu_h, Fw_h, S, x, prev, scal, Sf,
      zb, rb, gzb, grb, gin);
  quad_zr_gh<<<dim3(1024), 256, 0, stream>>>(S, Sf, prev, rb, gzb, grb,
      wz_s, uz_s, wr_s, ur_s, Fw_z, Fw_r, scal, Szb, G,
      x, gin, zb, Fu_h, Fw_h, hb, ghb, out_mu);
  quad_h<<<dim3(1024), 256, 0, stream>>>(S, Szb, prev, zb, hb, ghb,
      wh_s, uh_s, Fw_h, G, scal, out_sig);
}

// Round 11
// 151.659 us; speedup vs baseline: 1.8745x; 1.0722x over previous
//
#include <hip/hip_runtime.h>
#include <math.h>

#define UDIM 256
#define BATCH 64
#define MATN 65536   // 256*256
#define PITCH 280    // LDS row pitch (bf16): 560B = 16B-aligned
#define GG_BASE 256
#define TRG_BASE 1280

typedef __bf16 bf16x8 __attribute__((ext_vector_type(8)));
typedef float  f32x4  __attribute__((ext_vector_type(4)));

__device__ __forceinline__ float softplusf(float x) { return log1pf(expf(x)); }
__device__ __forceinline__ float sigmoidf_(float x) { return 1.f/(1.f+expf(-x)); }

// Fragment-direct layout (verified): chunk(rt,kt) = rows rt*16..+15 x k
// kt*32..+31; lane = (row&15) | ((k>>3)&3)<<4; 8 contiguous bf16 per lane.
__device__ __forceinline__ bf16x8 frag_load(const __bf16* base, int rt, int kt, int lane) {
  return *(const bf16x8*)(base + (((size_t)(rt*8 + kt))*64 + lane)*8);
}

__device__ __forceinline__ bf16x8 cvt8(const float* p) {
  const float4 f0 = *(const float4*)p;
  const float4 f1 = *(const float4*)(p + 4);
  bf16x8 v;
  v[0]=(__bf16)f0.x; v[1]=(__bf16)f0.y; v[2]=(__bf16)f0.z; v[3]=(__bf16)f0.w;
  v[4]=(__bf16)f1.x; v[5]=(__bf16)f1.y; v[6]=(__bf16)f1.z; v[7]=(__bf16)f1.w;
  return v;
}

#define MFMA16 __builtin_amdgcn_mfma_f32_16x16x32_bf16

// ---------------------------------------------------------------------------
// prep_all (round-10 verbatim): grid EXACTLY 1024.
//   0..63 : weight transposes Wz/Wr/Uh/Wh -> fragment-direct bf16
//   64..79: scalar reductions xx/pp/trS (plain stores)
//   80..111: z/r gates with self-transposed weight slices; GG to unique slots
//   all   : one S->Sf conversion chunk
// ---------------------------------------------------------------------------
__global__ __launch_bounds__(256) void prep_all(
    const float* __restrict__ Uz, const float* __restrict__ Wz,
    const float* __restrict__ Ur, const float* __restrict__ Wr,
    const float* __restrict__ Uh, const float* __restrict__ Wh,
    __bf16* __restrict__ Fw_z, __bf16* __restrict__ Fw_r,
    __bf16* __restrict__ Fu_h, __bf16* __restrict__ Fw_h,
    const float* __restrict__ S, const float* __restrict__ x,
    const float* __restrict__ prev, float* __restrict__ scal,
    __bf16* __restrict__ Sf,
    float* __restrict__ zb, float* __restrict__ rb,
    float* __restrict__ gzb, float* __restrict__ grb,
    float* __restrict__ gin)
{
  const int bid = blockIdx.x;
  const int t = threadIdx.x;
  const int w = t >> 6, l = t & 63, r = l & 15, q = l >> 4;

  __shared__ __align__(16) unsigned char LDSU[16896];

  if (bid < 64) {
    // ---- weight transpose role ----
    const int mat = bid >> 4, tl = bid & 15;
    const int n0 = (tl & 3)*64, k0 = (tl >> 2)*64;
    const float* W; __bf16* F;
    switch (mat) {
      case 0: W = Wz; F = Fw_z; break;  case 1: W = Wr; F = Fw_r; break;
      case 2: W = Uh; F = Fu_h; break;  default: W = Wh; F = Fw_h; break;
    }
    float (*tile)[65] = (float (*)[65])LDSU;
    const int tx = t & 15, ty = t >> 4;
#pragma unroll
    for (int rr = 0; rr < 4; ++rr) {
      const int row = ty*4 + rr;
      const float4 f = *(const float4*)(W + (size_t)(k0 + row)*UDIM + n0 + tx*4);
      tile[row][tx*4+0] = f.x; tile[row][tx*4+1] = f.y;
      tile[row][tx*4+2] = f.z; tile[row][tx*4+3] = f.w;
    }
    __syncthreads();
#pragma unroll
    for (int ss = 0; ss < 2; ++ss) {
      const int s = t + ss*256;
      const int rt_l = s >> 7, kt_l = (s >> 6) & 1, lane = s & 63;
      const int nl = rt_l*16 + (lane & 15), kb = kt_l*32 + (lane >> 4)*8;
      __align__(16) __bf16 tmp[8];
#pragma unroll
      for (int e = 0; e < 8; ++e) tmp[e] = (__bf16)tile[kb + e][nl];
      *(uint4*)(F + (((size_t)((((n0 >> 4) + rt_l)*8) + (k0 >> 5) + kt_l))*64 + lane)*8)
          = *(const uint4*)tmp;
    }
  } else if (bid < 80) {
    // ---- scalar reductions role ----
    const int blk = bid - 64;
    const int b0 = blk*4 + (t >> 6);
    const float4 xv = *(const float4*)(x + b0*UDIM + l*4);
    float s0 = xv.x*xv.x + xv.y*xv.y + xv.z*xv.z + xv.w*xv.w;
    const float4 pv = *(const float4*)(prev + b0*UDIM + l*4);
    float s1 = pv.x*pv.x + pv.y*pv.y + pv.z*pv.z + pv.w*pv.w;
    float s2 = 0.f;
#pragma unroll
    for (int e = 0; e < 4; ++e)
      s2 += S[(size_t)b0*MATN + (size_t)(l*4 + e)*257];
    for (int off = 32; off; off >>= 1) {
      s0 += __shfl_down(s0, off);
      s1 += __shfl_down(s1, off);
      s2 += __shfl_down(s2, off);
    }
    if (l == 0) { scal[b0] = s0; scal[64 + b0] = s1; scal[128 + b0] = s2; }
  } else if (bid < 112) {
    // ---- z/r gates role (self-transposed weight slices) ----
    const int u2 = bid - 80;
    const int g = u2 >> 4, un = u2 & 15;
    const int n0 = un * 16;
    const float* Um = g ? Ur : Uz;
    const float* Wm = g ? Wr : Wz;
    __bf16 (*Ut)[16][264] = (__bf16 (*)[16][264])LDSU;
    {
      float uv[16], wv[16];
      const float* ur_ = Um + (size_t)t*UDIM + n0;
      const float* wr_ = Wm + (size_t)t*UDIM + n0;
#pragma unroll
      for (int p4 = 0; p4 < 4; ++p4) {
        *(float4*)&uv[p4*4] = *(const float4*)(ur_ + p4*4);
        *(float4*)&wv[p4*4] = *(const float4*)(wr_ + p4*4);
      }
#pragma unroll
      for (int e = 0; e < 16; ++e) {
        Ut[0][e][t] = (__bf16)uv[e];
        Ut[1][e][t] = (__bf16)wv[e];
      }
    }
    __syncthreads();

    const int mrow = w*16 + r;
    f32x4 acc = {};
#pragma unroll
    for (int ks = 0; ks < 16; ++ks) {
      const int k0 = ks*32;
      const float* asrc;
      int src, koff;
      if (k0 < 256) { asrc = x    + (size_t)mrow*UDIM + k0         + q*8; src = 0; koff = k0; }
      else          { asrc = prev + (size_t)mrow*UDIM + (k0 - 256) + q*8; src = 1; koff = k0 - 256; }
      const bf16x8 af = cvt8(asrc);
      const bf16x8 bv = *(const bf16x8*)&Ut[src][r][koff + q*8];
      acc = MFMA16(af, bv, acc, 0, 0, 0);
    }
    const int n = n0 + r;
    if (g == 0) {
#pragma unroll
      for (int v = 0; v < 4; ++v) {
        const int m = w*16 + q*4 + v;
        const float zv = sigmoidf_(acc[v]);
        zb[m*UDIM + n]  = zv;
        gzb[m*UDIM + n] = zv * (1.f - zv);
      }
    } else {
      float ggp[4];
#pragma unroll
      for (int v = 0; v < 4; ++v) {
        const int m = w*16 + q*4 + v;
        const float rv = sigmoidf_(acc[v]);
        const float pv = prev[m*UDIM + n];
        const float g2 = pv * rv;
        rb[m*UDIM + n]  = rv;
        grb[m*UDIM + n] = rv * (1.f - rv);
        gin[m*UDIM + n] = g2;
        ggp[v] = g2 * g2;
      }
#pragma unroll
      for (int s2 = 1; s2 < 16; s2 <<= 1)
#pragma unroll
        for (int v = 0; v < 4; ++v) ggp[v] += __shfl_xor(ggp[v], s2);
      if (r == 0)
#pragma unroll
        for (int v = 0; v < 4; ++v)
          scal[GG_BASE + (w*16 + q*4 + v)*16 + un] = ggp[v];   // unique slot
    }
  }

  // ---- all blocks: S -> Sf fragment-direct bf16 conversion (chunk = bid) ----
  {
    const int c = bid;
    const int bx = c & 3, by = (c >> 2) & 3, b = c >> 4;
    const size_t sb = (size_t)b * MATN;
#pragma unroll
    for (int ss = 0; ss < 2; ++ss) {
      const int s = t + ss*256;
      const int chunk = s >> 6, lane = s & 63;
      const int rt_l = chunk >> 1, kt_l = chunk & 1;
      const int row = by*64 + rt_l*16 + (lane & 15);
      const int col = bx*64 + kt_l*32 + (lane >> 4)*8;
      const bf16x8 v = cvt8(S + sb + (size_t)row*UDIM + col);
      *(bf16x8*)(Sf + sb + (((size_t)((by*4 + rt_l)*8 + bx*2 + kt_l))*64 + lane)*8) = v;
    }
  }
}

// ---------------------------------------------------------------------------
// quad_zr_gh: grid EXACTLY 1024.  Block (s,b), fused z/r gates, batched
// loads.  gates_h rider now 16-WAY SPLIT (rider-lite): blocks 0..15 each
// compute one 16-column h-gate tile (~2.5µs) before their main quad —
// critical path drops from rider(10µs)+quad to riderlite(2.5µs)+quad.
// Epilogue j-rows (gzb/grb/prev/rb) prefetched BEFORE the right GEMMs.
// trG block-reduced to unique slot scal[TRG_BASE + b*16 + s] (no atomics).
// ---------------------------------------------------------------------------
__global__ __launch_bounds__(256, 4) void quad_zr_gh(
    const float* __restrict__ S, const __bf16* __restrict__ Sf,
    const float* __restrict__ prev,
    const float* __restrict__ rb, const float* __restrict__ gzb,
    const float* __restrict__ grb,
    const float* __restrict__ wz_s, const float* __restrict__ uz_s,
    const float* __restrict__ wr_s, const float* __restrict__ ur_s,
    const __bf16* __restrict__ Fw_z, const __bf16* __restrict__ Fw_r,
    float* __restrict__ scal, __bf16* __restrict__ Szb, __bf16* __restrict__ G,
    const float* __restrict__ x, const float* __restrict__ gin,
    const float* __restrict__ zb,
    const __bf16* __restrict__ Fu_h, const __bf16* __restrict__ Fw_h,
    float* __restrict__ hb, float* __restrict__ ghb, float* __restrict__ mu_out)
{
  const int bid = blockIdx.x;
  const int t = threadIdx.x, w = t >> 6, l = t & 63, r = l & 15, q = l >> 4;
  const int s = bid >> 6, b = bid & 63;

  __shared__ __align__(16) __bf16 T[2*16*PITCH];
  __shared__ float red4[4];
  __bf16* Tz = T;
  __bf16* Tr = T + 16*PITCH;

  if (bid < 16) {
    // ---- rider-lite: one 16-column h-gate tile (un = bid) ----
    const int un = bid;
    const int mrow = w*16 + r;
    f32x4 acc = {};
#pragma unroll
    for (int kq = 0; kq < 4; ++kq) {
      bf16x8 af[4], bv[4];
#pragma unroll
      for (int u = 0; u < 4; ++u) {
        const int k0 = (kq*4 + u)*32;
        if (k0 < 256) {
          af[u] = cvt8(x   + (size_t)mrow*UDIM + k0 + q*8);
          bv[u] = frag_load(Fu_h, un, k0 >> 5, l);
        } else {
          af[u] = cvt8(gin + (size_t)mrow*UDIM + (k0 - 256) + q*8);
          bv[u] = frag_load(Fw_h, un, (k0 - 256) >> 5, l);
        }
      }
#pragma unroll
      for (int u = 0; u < 4; ++u) acc = MFMA16(af[u], bv[u], acc, 0, 0, 0);
    }
    const int n = un*16 + r;
#pragma unroll
    for (int v = 0; v < 4; ++v) {
      const int m = w*16 + q*4 + v;
      const float hv = tanhf(acc[v]);
      const float zv = zb[m*UDIM + n];
      hb[m*UDIM + n]  = hv;
      ghb[m*UDIM + n] = 1.f - hv*hv;
      mu_out[m*UDIM + n] = zv * prev[m*UDIM + n] + (1.f - zv) * hv;
    }
  }

  const size_t sb = (size_t)b * MATN;
  const __bf16* Sfb = Sf + sb;

  // ---- left GEMMs: kt-pair batched loads, each Sf frag feeds both gates ----
  f32x4 az[4] = {}, ar[4] = {};
#pragma unroll
  for (int kp = 0; kp < 4; ++kp) {
    bf16x8 wzf[2], wrf[2], sv[2][4];
#pragma unroll
    for (int u = 0; u < 2; ++u) {
      const int kt = kp*2 + u;
      wzf[u] = frag_load(Fw_z, s, kt, l);
      wrf[u] = frag_load(Fw_r, s, kt, l);
#pragma unroll
      for (int ct = 0; ct < 4; ++ct) sv[u][ct] = frag_load(Sfb, w*4 + ct, kt, l);
    }
#pragma unroll
    for (int u = 0; u < 2; ++u)
#pragma unroll
      for (int ct = 0; ct < 4; ++ct) {
        az[ct] = MFMA16(wzf[u], sv[u][ct], az[ct], 0, 0, 0);
        ar[ct] = MFMA16(wrf[u], sv[u][ct], ar[ct], 0, 0, 0);
      }
  }
#pragma unroll
  for (int ct = 0; ct < 4; ++ct)
#pragma unroll
    for (int v = 0; v < 4; ++v) {
      Tz[(q*4 + v)*PITCH + w*64 + ct*16 + r] = (__bf16)az[ct][v];
      Tr[(q*4 + v)*PITCH + w*64 + ct*16 + r] = (__bf16)ar[ct][v];
    }
  __syncthreads();

  // ---- epilogue operand prefetch (ALL of it, hides under right GEMMs) ----
  const int ib = s*16 + q*4;
  const f32x4 gz4 = *(const f32x4*)(gzb + b*UDIM + ib);
  const f32x4 gr4 = *(const f32x4*)(grb + b*UDIM + ib);
  const f32x4 pp4 = *(const f32x4*)(prev + b*UDIM + ib);
  const f32x4 rr4 = *(const f32x4*)(rb + b*UDIM + ib);
  float Sv[16], gjz[4], gjr[4], pjv[4], rjv[4];
#pragma unroll
  for (int ct = 0; ct < 4; ++ct) {
    const int j = (w*4 + ct)*16 + r;
    gjz[ct] = gzb[b*UDIM + j];
    gjr[ct] = grb[b*UDIM + j];
    pjv[ct] = prev[b*UDIM + j];
    rjv[ct] = rb[b*UDIM + j];
#pragma unroll
    for (int v = 0; v < 4; ++v)
      Sv[ct*4 + v] = S[sb + (size_t)(ib + v)*UDIM + j];
  }
  const float xx = scal[b];
  const float dscal = scal[64 + b] + scal[128 + b];   // pp + trS

  // ---- right GEMMs from LDS (per-kt batched FW loads) ----
  f32x4 qz[4] = {}, qr[4] = {};
#pragma unroll
  for (int kt = 0; kt < 8; ++kt) {
    bf16x8 bwz[4], bwr[4];
#pragma unroll
    for (int ct = 0; ct < 4; ++ct) {
      bwz[ct] = frag_load(Fw_z, w*4 + ct, kt, l);
      bwr[ct] = frag_load(Fw_r, w*4 + ct, kt, l);
    }
    const bf16x8 atz = *(const bf16x8*)&Tz[r*PITCH + kt*32 + q*8];
    const bf16x8 atr = *(const bf16x8*)&Tr[r*PITCH + kt*32 + q*8];
#pragma unroll
    for (int ct = 0; ct < 4; ++ct) {
      qz[ct] = MFMA16(atz, bwz[ct], qz[ct], 0, 0, 0);
      qr[ct] = MFMA16(atr, bwr[ct], qr[ct], 0, 0, 0);
    }
  }

  // ---- z epilogue -> Szb (C-linear bf16) ----
  {
    __align__(16) __bf16 o16[16];
#pragma unroll
    for (int ct = 0; ct < 4; ++ct) {
      const int j = (w*4 + ct)*16 + r;
#pragma unroll
      for (int v = 0; v < 4; ++v) {
        const int i = ib + v;
        float qv = qz[ct][v];
        if (i == j) qv += dscal*softplusf(wz_s[i]) + xx*softplusf(uz_s[i]);
        o16[ct*4 + v] = (__bf16)(qv * gz4[v] * gjz[ct]);
      }
    }
    __bf16* dst = Szb + ((size_t)(b*16 + s)*256 + t)*16;
    *(uint4*)dst       = *(const uint4*)&o16[0];
    *(uint4*)(dst + 8) = *(const uint4*)&o16[8];
  }

  // ---- r epilogue -> sigma_g + trG (block-reduced), bounce Tr -> G ----
  {
    float gvals[16];
    float trg = 0.f;
#pragma unroll
    for (int ct = 0; ct < 4; ++ct) {
      const int j = (w*4 + ct)*16 + r;
#pragma unroll
      for (int v = 0; v < 4; ++v) {
        const int i = ib + v;
        float qv = qr[ct][v];
        if (i == j) qv += dscal*softplusf(wr_s[i]) + xx*softplusf(ur_s[i]);
        const float Sg = qv * gr4[v] * gjr[ct];
        const float sv = Sv[ct*4 + v];
        const float go = Sg*(sv + pp4[v]*pjv[ct]) + rr4[v]*rjv[ct]*sv;
        gvals[ct*4 + v] = go;
        if (i == j) trg += go;
      }
    }
    // block-reduce trg -> unique slot (no atomic, no memset needed)
    for (int off = 32; off; off >>= 1) trg += __shfl_down(trg, off);
    if (l == 0) red4[w] = trg;

    __syncthreads();            // all right-GEMM Tr reads complete; red4 ready
    if (t == 0)
      scal[TRG_BASE + b*16 + s] = red4[0] + red4[1] + red4[2] + red4[3];
#pragma unroll
    for (int ct = 0; ct < 4; ++ct)
#pragma unroll
      for (int v = 0; v < 4; ++v)
        Tr[(q*4 + v)*PITCH + w*64 + ct*16 + r] = (__bf16)gvals[ct*4 + v];
    __syncthreads();
#pragma unroll
    for (int ee = 0; ee < 2; ++ee) {
      const int e = t + ee*256;
      const int kt = e >> 6, le = e & 63;
      const uint4 vv = *(const uint4*)&Tr[(le & 15)*PITCH + kt*32 + (le >> 4)*8];
      *(uint4*)(G + sb + (((size_t)(s*8 + kt))*64 + le)*8) = vv;
    }
  }
}

// ---------------------------------------------------------------------------
// quad_h (round-10 verbatim): grid 1024, one strip per block, batched loads
// + full epilogue prefetch.  dscal = sum GG[b] + TRG[b] (8 vector loads).
// ---------------------------------------------------------------------------
__global__ __launch_bounds__(256, 4) void quad_h(
    const float* __restrict__ S, const __bf16* __restrict__ Szb,
    const float* __restrict__ prev, const float* __restrict__ zb,
    const float* __restrict__ hb, const float* __restrict__ ghb,
    const float* __restrict__ wh_s, const float* __restrict__ uh_s,
    const __bf16* __restrict__ Fw_h, const __bf16* __restrict__ G,
    const float* __restrict__ scal, float* __restrict__ out_sig)
{
  const int bid = blockIdx.x;
  const int s = bid >> 6, b = bid & 63;
  const size_t sb = (size_t)b * MATN;
  const int t = threadIdx.x, w = t >> 6, l = t & 63, r = l & 15, q = l >> 4;
  const __bf16* Gb = G + sb;

  __shared__ __align__(16) __bf16 Th[16*PITCH];

  // ---- left GEMM: kt-pair batched loads ----
  f32x4 ah[4] = {};
#pragma unroll
  for (int kp = 0; kp < 4; ++kp) {
    bf16x8 af[2], bv[2][4];
#pragma unroll
    for (int u = 0; u < 2; ++u) {
      const int kt = kp*2 + u;
      af[u] = frag_load(Fw_h, s, kt, l);
#pragma unroll
      for (int ct = 0; ct < 4; ++ct) bv[u][ct] = frag_load(Gb, w*4 + ct, kt, l);
    }
#pragma unroll
    for (int u = 0; u < 2; ++u)
#pragma unroll
      for (int ct = 0; ct < 4; ++ct)
        ah[ct] = MFMA16(af[u], bv[u][ct], ah[ct], 0, 0, 0);
  }
#pragma unroll
  for (int ct = 0; ct < 4; ++ct)
#pragma unroll
    for (int v = 0; v < 4; ++v)
      Th[(q*4 + v)*PITCH + w*64 + ct*16 + r] = (__bf16)ah[ct][v];
  __syncthreads();

  // ---- epilogue operand prefetch (hides under right GEMM) ----
  const int ib = s*16 + q*4;
  const __bf16* szp = Szb + ((size_t)(b*16 + s)*256 + t)*16;
  __align__(16) __bf16 sz16[16];
  *(uint4*)&sz16[0] = *(const uint4*)szp;
  *(uint4*)&sz16[8] = *(const uint4*)(szp + 8);
  const f32x4 g4 = *(const f32x4*)(ghb + b*UDIM + ib);
  const f32x4 p4 = *(const f32x4*)(prev + b*UDIM + ib);
  const f32x4 z4 = *(const f32x4*)(zb + b*UDIM + ib);
  const f32x4 h4 = *(const f32x4*)(hb + b*UDIM + ib);
  float Sv[16], gjv[4], pjv[4], zjv[4], hjv[4];
#pragma unroll
  for (int ct = 0; ct < 4; ++ct) {
    const int j = (w*4 + ct)*16 + r;
    gjv[ct] = ghb[b*UDIM + j];
    pjv[ct] = prev[b*UDIM + j];
    zjv[ct] = zb[b*UDIM + j];
    hjv[ct] = hb[b*UDIM + j];
#pragma unroll
    for (int v = 0; v < 4; ++v)
      Sv[ct*4 + v] = S[sb + (size_t)(ib + v)*UDIM + j];
  }
  const float xx = scal[b];
  float dscal = 0.f;
#pragma unroll
  for (int e = 0; e < 4; ++e) {
    const f32x4 a = *(const f32x4*)(scal + GG_BASE + b*16 + e*4);
    const f32x4 c = *(const f32x4*)(scal + TRG_BASE + b*16 + e*4);
    dscal += a[0]+a[1]+a[2]+a[3] + c[0]+c[1]+c[2]+c[3];
  }

  // ---- right GEMM from LDS ----
  f32x4 qh[4] = {};
#pragma unroll
  for (int kt = 0; kt < 8; ++kt) {
    bf16x8 bw[4];
#pragma unroll
    for (int ct = 0; ct < 4; ++ct) bw[ct] = frag_load(Fw_h, w*4 + ct, kt, l);
    const bf16x8 at = *(const bf16x8*)&Th[r*PITCH + kt*32 + q*8];
#pragma unroll
    for (int ct = 0; ct < 4; ++ct)
      qh[ct] = MFMA16(at, bw[ct], qh[ct], 0, 0, 0);
  }

#pragma unroll
  for (int ct = 0; ct < 4; ++ct) {
    const int j = (w*4 + ct)*16 + r;
#pragma unroll
    for (int v = 0; v < 4; ++v) {
      const int i = ib + v;
      float qv = qh[ct][v];
      if (i == j) qv += dscal*softplusf(wh_s[i]) + xx*softplusf(uh_s[i]);
      const float Sg = qv * g4[v] * gjv[ct];
      const float sv = Sv[ct*4 + v];
      const float sz = (float)sz16[ct*4 + v];
      float val = sv*(sz + z4[v]*zjv[ct])
                + sz*(p4[v] - h4[v])*(pjv[ct] - hjv[ct])
                + Sg*(sz + (1.f - z4[v])*(1.f - zjv[ct]));
      if (!isfinite(val)) val = 0.f;
      if (i == j) val = fabsf(val);
      out_sig[sb + (size_t)i*UDIM + j] = val;
    }
  }
}

// ---------------------------------------------------------------------------
extern "C" void kernel_launch(void* const* d_in, const int* in_sizes, int n_in,
                              void* d_out, int out_size, void* d_ws, size_t ws_size,
                              hipStream_t stream) {
  const float* x    = (const float*)d_in[0];
  const float* prev = (const float*)d_in[1];
  const float* S    = (const float*)d_in[2];
  const float* Uz   = (const float*)d_in[3];
  const float* uz_s = (const float*)d_in[4];
  const float* Wz   = (const float*)d_in[5];
  const float* wz_s = (const float*)d_in[6];
  const float* Ur   = (const float*)d_in[7];
  const float* ur_s = (const float*)d_in[8];
  const float* Wr   = (const float*)d_in[9];
  const float* wr_s = (const float*)d_in[10];
  const float* Uh   = (const float*)d_in[11];
  const float* uh_s = (const float*)d_in[12];
  const float* Wh   = (const float*)d_in[13];
  const float* wh_s = (const float*)d_in[14];

  float* out_mu  = (float*)d_out;
  float* out_sig = out_mu + BATCH*UDIM;

  float* ws   = (float*)d_ws;
  float* zb   = ws;
  float* rb   = zb  + BATCH*UDIM;
  float* gzb  = rb  + BATCH*UDIM;
  float* grb  = gzb + BATCH*UDIM;
  float* gin  = grb + BATCH*UDIM;
  float* hb   = gin + BATCH*UDIM;
  float* ghb  = hb  + BATCH*UDIM;
  float* scal = ghb + BATCH*UDIM;            // 2304 floats (all unique-slot)
  __bf16* bws  = (__bf16*)(scal + 2304);
  __bf16* Fw_z = bws;
  __bf16* Fw_r = Fw_z + MATN;
  __bf16* Fu_h = Fw_r + MATN;
  __bf16* Fw_h = Fu_h + MATN;
  const size_t BIG = (size_t)BATCH * MATN;
  __bf16* Szb = Fw_h + MATN;                 // [B,16,256,16] bf16 C-linear
  __bf16* G   = Szb + BIG;                   // [B,U,U] bf16 fragment-direct
  __bf16* Sf  = G + BIG;                     // [B,U,U] bf16 fragment-direct

  prep_all<<<dim3(1024), 256, 0, stream>>>(Uz, Wz, Ur, Wr, Uh, Wh,
      Fw_z, Fw_r, Fu_h, Fw_h, S, x, prev, scal, Sf,
      zb, rb, gzb, grb, gin);
  quad_zr_gh<<<dim3(1024), 256, 0, stream>>>(S, Sf, prev, rb, gzb, grb,
      wz_s, uz_s, wr_s, ur_s, Fw_z, Fw_r, scal, Szb, G,
      x, gin, zb, Fu_h, Fw_h, hb, ghb, out_mu);
  quad_h<<<dim3(1024), 256, 0, stream>>>(S, Szb, prev, zb, hb, ghb,
      wh_s, uh_s, Fw_h, G, scal, out_sig);
}